// Round 1
// baseline (2134.336 us; speedup 1.0000x reference)
//
#include <hip/hip_runtime.h>

// Graph-transformer MHA layer. N=50000 nodes, E=1600000 edges, IN_DIM=64, H=8, D=8 (H*D=64).
// Outputs: h_out [N*64] then e_out [E*64], fp32, concatenated in d_out.
//
// Structure:
//  1) memset wV accumulator (d_out h_out region) and z (in d_ws) to 0
//  2) proj_kernel: Q,K,V = h@W + b  (grid.y selects matrix), into d_ws
//  3) edge_kernel: pe = e@We+be; score = K[src]*Q[dst]*pe/sqrt(D); e_out = score;
//     s = exp(clip(sum_d score)); atomic wV[dst] += V[src]*s; z[dst] += s
//  4) div_kernel: h_out = wV / (z + 1e-6)

#define WAVE 64

// ---------------- node projection ----------------
// Each wave register-caches one W column per lane; 16 node rows staged in LDS
// per block iteration; each wave computes 4 nodes (4 independent FMA chains).
__global__ __launch_bounds__(256)
void proj_kernel(const float* __restrict__ hsrc,
                 const float* __restrict__ Wq, const float* __restrict__ bq,
                 const float* __restrict__ Wk, const float* __restrict__ bk,
                 const float* __restrict__ Wv, const float* __restrict__ bv,
                 float* __restrict__ Q, float* __restrict__ K, float* __restrict__ V,
                 int n)
{
    const float* W;
    const float* b;
    float* out;
    if (blockIdx.y == 0)      { W = Wq; b = bq; out = Q; }
    else if (blockIdx.y == 1) { W = Wk; b = bk; out = K; }
    else                      { W = Wv; b = bv; out = V; }

    const int t    = threadIdx.x;
    const int lane = t & 63;
    const int w    = t >> 6;

    float wcol[64];
#pragma unroll
    for (int k = 0; k < 64; ++k) wcol[k] = W[k * 64 + lane];
    const float bias = b[lane];

    __shared__ float4 sh[16][16];
    const float4* __restrict__ h4 = (const float4*)hsrc;

    const int ngroups = (n + 15) >> 4;
    for (int g = blockIdx.x; g < ngroups; g += gridDim.x) {
        const int base = g << 4;
        {
            const int rs = t >> 4, c4 = t & 15;
            float4 v = make_float4(0.f, 0.f, 0.f, 0.f);
            if (base + rs < n) v = h4[(size_t)(base + rs) * 16 + c4];
            __syncthreads();
            sh[rs][c4] = v;
            __syncthreads();
        }
        float acc0 = bias, acc1 = bias, acc2 = bias, acc3 = bias;
#pragma unroll
        for (int k4 = 0; k4 < 16; ++k4) {
            const float w0 = wcol[k4 * 4 + 0], w1 = wcol[k4 * 4 + 1];
            const float w2 = wcol[k4 * 4 + 2], w3 = wcol[k4 * 4 + 3];
            const float4 a = sh[w * 4 + 0][k4];
            const float4 bb = sh[w * 4 + 1][k4];
            const float4 c = sh[w * 4 + 2][k4];
            const float4 d = sh[w * 4 + 3][k4];
            acc0 = fmaf(a.w,  w3, fmaf(a.z,  w2, fmaf(a.y,  w1, fmaf(a.x,  w0, acc0))));
            acc1 = fmaf(bb.w, w3, fmaf(bb.z, w2, fmaf(bb.y, w1, fmaf(bb.x, w0, acc1))));
            acc2 = fmaf(c.w,  w3, fmaf(c.z,  w2, fmaf(c.y,  w1, fmaf(c.x,  w0, acc2))));
            acc3 = fmaf(d.w,  w3, fmaf(d.z,  w2, fmaf(d.y,  w1, fmaf(d.x,  w0, acc3))));
        }
        const int n0 = base + w * 4;
        if (n0 + 0 < n) out[(size_t)(n0 + 0) * 64 + lane] = acc0;
        if (n0 + 1 < n) out[(size_t)(n0 + 1) * 64 + lane] = acc1;
        if (n0 + 2 < n) out[(size_t)(n0 + 2) * 64 + lane] = acc2;
        if (n0 + 3 < n) out[(size_t)(n0 + 3) * 64 + lane] = acc3;
    }
}

// ---------------- edge kernel ----------------
__global__ __launch_bounds__(256)
void edge_kernel(const float* __restrict__ e,
                 const float* __restrict__ We, const float* __restrict__ be,
                 const int* __restrict__ src, const int* __restrict__ dst,
                 const float* __restrict__ Q, const float* __restrict__ K,
                 const float* __restrict__ V,
                 float* __restrict__ e_out, float* __restrict__ wV,
                 float* __restrict__ z, int E)
{
    const int t    = threadIdx.x;
    const int lane = t & 63;
    const int w    = t >> 6;

    float wcol[64];
#pragma unroll
    for (int k = 0; k < 64; ++k) wcol[k] = We[k * 64 + lane];
    const float bias = be[lane];
    const float inv_sqrt_d = 0.35355339059327373f; // 1/sqrt(8)

    __shared__ float4 se[16][16];
    const float4* __restrict__ e4 = (const float4*)e;

    const int ngroups = (E + 15) >> 4;
    for (int g = blockIdx.x; g < ngroups; g += gridDim.x) {
        const int base = g << 4;
        {
            const int rs = t >> 4, c4 = t & 15;
            float4 v = make_float4(0.f, 0.f, 0.f, 0.f);
            if (base + rs < E) v = e4[(size_t)(base + rs) * 16 + c4];
            __syncthreads();
            se[rs][c4] = v;
            __syncthreads();
        }
        // 4 edges per wave, 4 independent accumulator chains
        float acc[4];
        acc[0] = bias; acc[1] = bias; acc[2] = bias; acc[3] = bias;
#pragma unroll
        for (int k4 = 0; k4 < 16; ++k4) {
            const float w0 = wcol[k4 * 4 + 0], w1 = wcol[k4 * 4 + 1];
            const float w2 = wcol[k4 * 4 + 2], w3 = wcol[k4 * 4 + 3];
            const float4 a = se[w * 4 + 0][k4];
            const float4 bb = se[w * 4 + 1][k4];
            const float4 c = se[w * 4 + 2][k4];
            const float4 d = se[w * 4 + 3][k4];
            acc[0] = fmaf(a.w,  w3, fmaf(a.z,  w2, fmaf(a.y,  w1, fmaf(a.x,  w0, acc[0]))));
            acc[1] = fmaf(bb.w, w3, fmaf(bb.z, w2, fmaf(bb.y, w1, fmaf(bb.x, w0, acc[1]))));
            acc[2] = fmaf(c.w,  w3, fmaf(c.z,  w2, fmaf(c.y,  w1, fmaf(c.x,  w0, acc[2]))));
            acc[3] = fmaf(d.w,  w3, fmaf(d.z,  w2, fmaf(d.y,  w1, fmaf(d.x,  w0, acc[3]))));
        }
#pragma unroll
        for (int m = 0; m < 4; ++m) {
            const int eid = base + w * 4 + m;
            if (eid < E) {
                const int se_ = src[eid];
                const int de_ = dst[eid];
                const float kv = K[(size_t)se_ * 64 + lane];
                const float qv = Q[(size_t)de_ * 64 + lane];
                const float score = kv * qv * inv_sqrt_d * acc[m];
                e_out[(size_t)eid * 64 + lane] = score;
                float hs = score;
                hs += __shfl_xor(hs, 1);
                hs += __shfl_xor(hs, 2);
                hs += __shfl_xor(hs, 4);
                const float sg = expf(fminf(fmaxf(hs, -5.f), 5.f));
                const float vv = V[(size_t)se_ * 64 + lane];
                atomicAdd(&wV[(size_t)de_ * 64 + lane], vv * sg);
                if ((lane & 7) == 0) atomicAdd(&z[(size_t)de_ * 8 + (lane >> 3)], sg);
            }
        }
    }
}

// ---------------- final divide ----------------
__global__ __launch_bounds__(256)
void div_kernel(float* __restrict__ hout, const float* __restrict__ z, int total)
{
    const int i = blockIdx.x * 256 + threadIdx.x;
    if (i < total) {
        hout[i] = hout[i] / (z[i >> 3] + 1e-6f);
    }
}

extern "C" void kernel_launch(void* const* d_in, const int* in_sizes, int n_in,
                              void* d_out, int out_size, void* d_ws, size_t ws_size,
                              hipStream_t stream)
{
    const float* h  = (const float*)d_in[0];
    const float* e  = (const float*)d_in[1];
    const float* Wq = (const float*)d_in[2];
    const float* bq = (const float*)d_in[3];
    const float* Wk = (const float*)d_in[4];
    const float* bk = (const float*)d_in[5];
    const float* Wv = (const float*)d_in[6];
    const float* bv = (const float*)d_in[7];
    const float* We = (const float*)d_in[8];
    const float* be = (const float*)d_in[9];
    const int* src  = (const int*)d_in[10];
    const int* dst  = (const int*)d_in[11];

    const int N = in_sizes[0] / 64;
    const int E = in_sizes[1] / 64;

    float* hout  = (float*)d_out;                    // [N*64] — doubles as wV accumulator
    float* e_out = (float*)d_out + (size_t)N * 64;   // [E*64]

    float* Q = (float*)d_ws;
    float* K = Q + (size_t)N * 64;
    float* V = K + (size_t)N * 64;
    float* z = V + (size_t)N * 64;                   // [N*8]

    // zero accumulators (graph-capture-safe async memsets)
    hipMemsetAsync(hout, 0, (size_t)N * 64 * sizeof(float), stream);
    hipMemsetAsync(z, 0, (size_t)N * 8 * sizeof(float), stream);

    // 1) Q,K,V projections
    proj_kernel<<<dim3(512, 3), dim3(256), 0, stream>>>(
        h, Wq, bq, Wk, bk, Wv, bv, Q, K, V, N);

    // 2) edge pass
    const int egroups = (E + 15) >> 4;
    const int eblocks = egroups < 2048 ? egroups : 2048;
    edge_kernel<<<dim3(eblocks), dim3(256), 0, stream>>>(
        e, We, be, src, dst, Q, K, V, e_out, hout, z, E);

    // 3) h_out = wV / (z + 1e-6)
    const int total = N * 64;
    div_kernel<<<dim3((total + 255) / 256), dim3(256), 0, stream>>>(hout, z, total);
}